// Round 1
// baseline (1391.608 us; speedup 1.0000x reference)
//
#include <hip/hip_runtime.h>
#include <hip/hip_bf16.h>

// Problem constants
#define NTOK   65536          // 32*2048 tokens
#define IND    768
#define HID    512
#define CBD    256
#define CBS    512

// d_out layout (floats): recon[NTOK*IND], indices-as-float[NTOK], loss[1]
#define OUT_IDX_OFF   ((size_t)NTOK * IND)            // 50331648
#define OUT_LOSS_OFF  (OUT_IDX_OFF + NTOK)            // 50397184

// ws layout (float elements)
#define WS_H      ((size_t)0)                          // h [NTOK*HID]
#define WS_Z      ((size_t)NTOK * HID)                 // z [NTOK*CBD]
#define WS_CBT    (WS_Z + (size_t)NTOK * CBD)          // cbT [CBD*CBS]
#define WS_TABLE  (WS_CBT + (size_t)CBD * CBS)         // ReconTable [CBS*IND]
#define WS_CSQ    (WS_TABLE + (size_t)CBS * IND)       // c_sq [CBS]
#define WS_ZSQ    (WS_CSQ + CBS)                       // zsq [NTOK]
#define WS_IDX    (WS_ZSQ + NTOK)                      // idx int [NTOK]
#define WS_ACC    (WS_IDX + NTOK)                      // accum [1]

// ---------------------------------------------------------------------------
// Precompute: c_sq, cbT (transposed codebook), ReconTable = dec(cb)
// one block per code, 256 threads
// ---------------------------------------------------------------------------
__global__ __launch_bounds__(256) void precompute_kernel(
    const float* __restrict__ cb, const float* __restrict__ W3,
    const float* __restrict__ b3, const float* __restrict__ W4,
    const float* __restrict__ b4, float* __restrict__ cbT,
    float* __restrict__ c_sq, float* __restrict__ table)
{
    __shared__ float crow[CBD];
    __shared__ float h2[HID];
    const int c = blockIdx.x;
    const int t = threadIdx.x;

    crow[t] = cb[(size_t)c * CBD + t];
    __syncthreads();

    // c_sq via wave 0
    if (t < 64) {
        float s = 0.f;
        #pragma unroll
        for (int k = 0; k < 4; ++k) { float v = crow[t + 64*k]; s = fmaf(v, v, s); }
        #pragma unroll
        for (int off = 32; off; off >>= 1) s += __shfl_down(s, off, 64);
        if (t == 0) c_sq[c] = s;
    }
    // transpose write (uncoalesced but tiny)
    cbT[(size_t)t * CBS + c] = crow[t];

    // h2 = relu(crow @ W3 + b3)   [HID]
    #pragma unroll
    for (int s = 0; s < 2; ++s) {
        int j = t + s * 256;
        float acc = b3[j];
        for (int k = 0; k < CBD; ++k) acc = fmaf(crow[k], W3[(size_t)k * HID + j], acc);
        h2[j] = fmaxf(acc, 0.f);
    }
    __syncthreads();

    // table row = h2 @ W4 + b4   [IND]
    #pragma unroll
    for (int s = 0; s < 3; ++s) {
        int j = t + s * 256;
        float acc = b4[j];
        for (int k = 0; k < HID; ++k) acc = fmaf(h2[k], W4[(size_t)k * IND + j], acc);
        table[(size_t)c * IND + j] = acc;
    }
}

// ---------------------------------------------------------------------------
// fp32 GEMM: C[M,N] = act(A[M,K] @ B[K,N] + bias[N])
// 128x128 block tile, BK=16, 256 threads, 8x8 per thread
// ---------------------------------------------------------------------------
__global__ __launch_bounds__(256, 4) void gemm_kernel(
    const float* __restrict__ A, const float* __restrict__ B,
    const float* __restrict__ bias, float* __restrict__ C,
    int M, int N, int K, int relu)
{
    __shared__ __align__(16) float As[16 * 132];   // [k][m], pad 4
    __shared__ __align__(16) float Bs[16 * 132];   // [k][n], pad 4
    const int tid = threadIdx.x;
    const int tx = tid & 15;          // 16 col-groups
    const int ty = tid >> 4;          // 16 row-groups
    const int m0 = blockIdx.y * 128;
    const int n0 = blockIdx.x * 128;

    float acc[8][8] = {};

    for (int k0 = 0; k0 < K; k0 += 16) {
        // stage A: 128x16 = 512 float4 slots
        #pragma unroll
        for (int s = 0; s < 2; ++s) {
            int slot = tid + s * 256;
            int m = slot >> 2, kg = (slot & 3) << 2;
            float4 v = *(const float4*)(A + (size_t)(m0 + m) * K + k0 + kg);
            As[(kg + 0) * 132 + m] = v.x;
            As[(kg + 1) * 132 + m] = v.y;
            As[(kg + 2) * 132 + m] = v.z;
            As[(kg + 3) * 132 + m] = v.w;
        }
        // stage B: 16x128 = 512 float4 slots
        #pragma unroll
        for (int s = 0; s < 2; ++s) {
            int slot = tid + s * 256;
            int k = slot >> 5, ng = (slot & 31) << 2;
            *(float4*)&Bs[k * 132 + ng] =
                *(const float4*)(B + (size_t)(k0 + k) * N + n0 + ng);
        }
        __syncthreads();
        #pragma unroll
        for (int kk = 0; kk < 16; ++kk) {
            float a[8], b[8];
            *(float4*)&a[0] = *(const float4*)&As[kk * 132 + ty * 8];
            *(float4*)&a[4] = *(const float4*)&As[kk * 132 + ty * 8 + 4];
            *(float4*)&b[0] = *(const float4*)&Bs[kk * 132 + tx * 4];
            *(float4*)&b[4] = *(const float4*)&Bs[kk * 132 + tx * 4 + 64];
            #pragma unroll
            for (int i = 0; i < 8; ++i)
                #pragma unroll
                for (int j = 0; j < 8; ++j)
                    acc[i][j] = fmaf(a[i], b[j], acc[i][j]);
        }
        __syncthreads();
    }

    float4 bi0 = *(const float4*)(bias + n0 + tx * 4);
    float4 bi1 = *(const float4*)(bias + n0 + 64 + tx * 4);
    #pragma unroll
    for (int i = 0; i < 8; ++i) {
        int row = m0 + ty * 8 + i;
        float4 o0, o1;
        o0.x = acc[i][0] + bi0.x; o0.y = acc[i][1] + bi0.y;
        o0.z = acc[i][2] + bi0.z; o0.w = acc[i][3] + bi0.w;
        o1.x = acc[i][4] + bi1.x; o1.y = acc[i][5] + bi1.y;
        o1.z = acc[i][6] + bi1.z; o1.w = acc[i][7] + bi1.w;
        if (relu) {
            o0.x = fmaxf(o0.x, 0.f); o0.y = fmaxf(o0.y, 0.f);
            o0.z = fmaxf(o0.z, 0.f); o0.w = fmaxf(o0.w, 0.f);
            o1.x = fmaxf(o1.x, 0.f); o1.y = fmaxf(o1.y, 0.f);
            o1.z = fmaxf(o1.z, 0.f); o1.w = fmaxf(o1.w, 0.f);
        }
        *(float4*)(C + (size_t)row * N + n0 + tx * 4) = o0;
        *(float4*)(C + (size_t)row * N + n0 + 64 + tx * 4) = o1;
    }
}

// ---------------------------------------------------------------------------
// zsq[n] = ||z_n||^2 : one wave per token
// ---------------------------------------------------------------------------
__global__ __launch_bounds__(256) void zsq_kernel(
    const float* __restrict__ z, float* __restrict__ zsq)
{
    const int tok  = blockIdx.x * 4 + (threadIdx.x >> 6);
    const int lane = threadIdx.x & 63;
    float4 v = *(const float4*)(z + (size_t)tok * CBD + lane * 4);
    float s = v.x * v.x + v.y * v.y + v.z * v.z + v.w * v.w;
    #pragma unroll
    for (int off = 32; off; off >>= 1) s += __shfl_down(s, off, 64);
    if (lane == 0) zsq[tok] = s;
}

// ---------------------------------------------------------------------------
// VQ: dots = z @ cbT, argmin(c_sq - 2 dots), commit partial
// block = 64 tokens x all 512 codes, 512 threads, 8x8 per thread, BK=16
// ---------------------------------------------------------------------------
__global__ __launch_bounds__(512, 4) void vq_kernel(
    const float* __restrict__ z, const float* __restrict__ cbT,
    const float* __restrict__ c_sq, const float* __restrict__ zsq,
    float* __restrict__ idx_f, int* __restrict__ idx_i,
    float* __restrict__ accum)
{
    __shared__ __align__(16) float smem[16 * 68 + 16 * 516];   // 9344 floats
    float* As = smem;             // [16][68]
    float* Bs = smem + 16 * 68;   // [16][516]
    const int tid = threadIdx.x;
    const int tx = tid & 63;      // 64 code-groups
    const int ty = tid >> 6;      // 8 token-groups
    const int m0 = blockIdx.x * 64;

    float acc[8][8] = {};

    for (int k0 = 0; k0 < CBD; k0 += 16) {
        if (tid < 256) {
            int m = tid >> 2, kg = (tid & 3) << 2;
            float4 v = *(const float4*)(z + (size_t)(m0 + m) * CBD + k0 + kg);
            As[(kg + 0) * 68 + m] = v.x;
            As[(kg + 1) * 68 + m] = v.y;
            As[(kg + 2) * 68 + m] = v.z;
            As[(kg + 3) * 68 + m] = v.w;
        }
        #pragma unroll
        for (int s = 0; s < 4; ++s) {
            int slot = tid + s * 512;
            int k = slot >> 7, ng = (slot & 127) << 2;
            *(float4*)&Bs[k * 516 + ng] =
                *(const float4*)(cbT + (size_t)(k0 + k) * CBS + ng);
        }
        __syncthreads();
        #pragma unroll
        for (int kk = 0; kk < 16; ++kk) {
            float a[8], b[8];
            *(float4*)&a[0] = *(const float4*)&As[kk * 68 + ty * 8];
            *(float4*)&a[4] = *(const float4*)&As[kk * 68 + ty * 8 + 4];
            *(float4*)&b[0] = *(const float4*)&Bs[kk * 516 + tx * 4];
            *(float4*)&b[4] = *(const float4*)&Bs[kk * 516 + tx * 4 + 256];
            #pragma unroll
            for (int i = 0; i < 8; ++i)
                #pragma unroll
                for (int j = 0; j < 8; ++j)
                    acc[i][j] = fmaf(a[i], b[j], acc[i][j]);
        }
        __syncthreads();
    }

    // per-thread argmin over its 8 codes for each of its 8 tokens
    float csq[8];
    #pragma unroll
    for (int j = 0; j < 4; ++j) {
        csq[j]     = c_sq[tx * 4 + j];
        csq[4 + j] = c_sq[256 + tx * 4 + j];
    }
    float* red_v = smem;                    // [64][65]
    int*   red_i = (int*)(smem + 64 * 65);  // [64][65]
    #pragma unroll
    for (int i = 0; i < 8; ++i) {
        float bv = 3.4e38f; int bi = 0x7fffffff;
        #pragma unroll
        for (int j = 0; j < 8; ++j) {
            int code = (j < 4) ? (tx * 4 + j) : (256 + tx * 4 + (j - 4));
            float d = fmaf(-2.0f, acc[i][j], csq[j]);
            if (d < bv || (d == bv && code < bi)) { bv = d; bi = code; }
        }
        red_v[(ty * 8 + i) * 65 + tx] = bv;
        red_i[(ty * 8 + i) * 65 + tx] = bi;
    }
    __syncthreads();
    if (tid < 64) {
        float bv = red_v[tid * 65]; int bi = red_i[tid * 65];
        for (int t = 1; t < 64; ++t) {
            float v = red_v[tid * 65 + t]; int ii = red_i[tid * 65 + t];
            if (v < bv || (v == bv && ii < bi)) { bv = v; bi = ii; }
        }
        int tok = m0 + tid;
        idx_f[tok] = (float)bi;
        idx_i[tok] = bi;
        float commit = zsq[tok] + bv;   // ||z||^2 + c_sq[best] - 2*dot_best
        #pragma unroll
        for (int off = 32; off; off >>= 1) commit += __shfl_down(commit, off, 64);
        if (tid == 0) atomicAdd(accum, commit);
    }
}

// ---------------------------------------------------------------------------
// recon gather: out[tok] = ReconTable[idx[tok]]
// ---------------------------------------------------------------------------
__global__ __launch_bounds__(256) void gather_kernel(
    const int* __restrict__ idx, const float* __restrict__ table,
    float* __restrict__ out)
{
    unsigned i = blockIdx.x * 256u + threadIdx.x;   // float4 index, total NTOK*192
    unsigned tok = i / 192u;
    unsigned c = i - tok * 192u;
    int id = idx[tok];
    ((float4*)out)[i] = ((const float4*)table)[(size_t)id * 192 + c];
}

__global__ void finalize_kernel(const float* __restrict__ accum,
                                float* __restrict__ out_loss)
{
    out_loss[0] = accum[0] * (1.0f / 16777216.0f);   // mean over NTOK*CBD, COMMIT_W=1
}

// ---------------------------------------------------------------------------
extern "C" void kernel_launch(void* const* d_in, const int* in_sizes, int n_in,
                              void* d_out, int out_size, void* d_ws, size_t ws_size,
                              hipStream_t stream) {
    const float* x  = (const float*)d_in[0];
    const float* W1 = (const float*)d_in[1];
    const float* b1 = (const float*)d_in[2];
    const float* W2 = (const float*)d_in[3];
    const float* b2 = (const float*)d_in[4];
    const float* cb = (const float*)d_in[5];
    const float* W3 = (const float*)d_in[6];
    const float* b3 = (const float*)d_in[7];
    const float* W4 = (const float*)d_in[8];
    const float* b4 = (const float*)d_in[9];

    float* ws    = (float*)d_ws;
    float* h     = ws + WS_H;
    float* zbuf  = ws + WS_Z;
    float* cbT   = ws + WS_CBT;
    float* table = ws + WS_TABLE;
    float* c_sq  = ws + WS_CSQ;
    float* zsq   = ws + WS_ZSQ;
    int*   idx_i = (int*)(ws + WS_IDX);
    float* accum = ws + WS_ACC;

    float* out      = (float*)d_out;
    float* out_idx  = out + OUT_IDX_OFF;
    float* out_loss = out + OUT_LOSS_OFF;

    hipMemsetAsync(accum, 0, sizeof(float), stream);

    precompute_kernel<<<CBS, 256, 0, stream>>>(cb, W3, b3, W4, b4, cbT, c_sq, table);

    // h = relu(x @ W1 + b1)
    gemm_kernel<<<dim3(HID / 128, NTOK / 128), 256, 0, stream>>>(
        x, W1, b1, h, NTOK, HID, IND, 1);
    // z = h @ W2 + b2
    gemm_kernel<<<dim3(CBD / 128, NTOK / 128), 256, 0, stream>>>(
        h, W2, b2, zbuf, NTOK, CBD, HID, 0);

    zsq_kernel<<<NTOK / 4, 256, 0, stream>>>(zbuf, zsq);

    vq_kernel<<<NTOK / 64, 512, 0, stream>>>(zbuf, cbT, c_sq, zsq,
                                             out_idx, idx_i, accum);

    gather_kernel<<<(NTOK * (IND / 4)) / 256, 256, 0, stream>>>(idx_i, table, out);

    finalize_kernel<<<1, 1, 0, stream>>>(accum, out_loss);
}

// Round 3
// 1058.630 us; speedup vs baseline: 1.3145x; 1.3145x over previous
//
#include <hip/hip_runtime.h>

typedef unsigned short u16;
typedef unsigned int   u32;
typedef __attribute__((ext_vector_type(8))) short short8;
typedef __attribute__((ext_vector_type(4))) float f32x4;

#define NTOK 65536
#define IND  768
#define HID  512
#define CBD  256
#define CBS  512

// d_out layout (floats): recon[NTOK*IND], indices-as-float[NTOK], loss[1]
#define OUT_IDX_OFF   ((size_t)NTOK * IND)
#define OUT_LOSS_OFF  (OUT_IDX_OFF + NTOK)

// ws byte offsets (total 203,950,080 <= proven round-1 usage 203,950,084)
#define OFF_H      ((size_t)0)            // Hpack u32 [NTOK][HID]  = 134,217,728 B
#define OFF_Z      ((size_t)134217728)    // Zpack u32 [NTOK][CBD]  =  67,108,864 B
#define OFF_W1H    ((size_t)201326592)    // W1T hi u16 [HID][IND]
#define OFF_W1L    ((size_t)202113024)
#define OFF_W2H    ((size_t)202899456)    // W2T hi u16 [CBD][HID]
#define OFF_W2L    ((size_t)203161600)
#define OFF_CBH    ((size_t)203423744)    // CB  hi u16 [CBS][CBD]
#define OFF_CBL    ((size_t)203685888)
#define OFF_CSQ    ((size_t)203948032)    // c_sq f32 [CBS]
// aliases inside H region (H dead after GEMM2 consumes it; all writers below
// run after GEMM2 in stream order)
#define OFF_PART   ((size_t)0)            // partials float4 [NTOK][8]  = 8,388,608 B
#define OFF_TABLE  ((size_t)8388608)      // ReconTable f32 [CBS][IND]  = 1,572,864 B
#define OFF_ZSQ    ((size_t)9961472)      // zsq f32 [NTOK]             =   262,144 B
#define OFF_IDX    ((size_t)10223616)     // idx int [NTOK]
#define OFF_FLAGS  ((size_t)10485760)     // flag list int [NTOK]
#define OFF_CNT    ((size_t)10747904)     // [0]=flag_count int, [4]=accum float

__device__ __forceinline__ u16 f2bf(float f) {
    u32 u = __float_as_uint(f);
    return (u16)((u + 0x7fffu + ((u >> 16) & 1u)) >> 16);
}
__device__ __forceinline__ float bf2f(u16 h) {
    return __uint_as_float(((u32)h) << 16);
}

// ---------------------------------------------------------------------------
// codebook split + c_sq : one block per code
// ---------------------------------------------------------------------------
__global__ __launch_bounds__(256) void cbsplit(
    const float* __restrict__ cb, u16* __restrict__ hi, u16* __restrict__ lo,
    float* __restrict__ csq)
{
    int c = blockIdx.x, t = threadIdx.x;
    float v = cb[(size_t)c * CBD + t];
    u16 h = f2bf(v); u16 l = f2bf(v - bf2f(h));
    hi[(size_t)c * CBD + t] = h; lo[(size_t)c * CBD + t] = l;
    __shared__ float red[256];
    red[t] = v * v; __syncthreads();
    for (int s = 128; s; s >>= 1) { if (t < s) red[t] += red[t + s]; __syncthreads(); }
    if (!t) csq[c] = red[0];
}

// ---------------------------------------------------------------------------
// weight transpose+split: W [K,N] fp32 -> WT hi/lo bf16 [N,K]. block per n.
// ---------------------------------------------------------------------------
__global__ __launch_bounds__(256) void wsplit(
    const float* __restrict__ W, u16* __restrict__ hi, u16* __restrict__ lo,
    int K, int N)
{
    int n = blockIdx.x;
    for (int k = threadIdx.x; k < K; k += 256) {
        float v = W[(size_t)k * N + n];
        u16 h = f2bf(v); u16 l = f2bf(v - bf2f(h));
        hi[(size_t)n * K + k] = h; lo[(size_t)n * K + k] = l;
    }
}

// ---------------------------------------------------------------------------
// bf16x3 MFMA GEMM: 128x128 tile, BK=32, 256 thr (4 waves), 4x4 16x16x32 frags
// AMODE 0: A fp32 [M,K] (convert in staging)   AMODE 1: A packed hi|lo u32 [M,K]
// EPI 0: relu(acc+bias) -> packed u32          EPI 1: acc+bias -> packed u32
// EPI 2: dist = bias[n] - 2*acc; per-row/wave-col top2 -> partials[row][bx*2+wcol]
// ---------------------------------------------------------------------------
template<int AMODE, int EPI>
__global__ __launch_bounds__(256, 2) void gemm3(
    const float* __restrict__ Af, const u32* __restrict__ Apk,
    const u16* __restrict__ Bhi, const u16* __restrict__ Blo,
    const float* __restrict__ bias,
    u32* __restrict__ Opk, float* __restrict__ Opart,
    int M, int N, int K)
{
    __shared__ u16 lds[4 * 128 * 40];         // 40 KB: Ahi, Alo, Bhi, Blo [128][40]
    u16* sAh = lds;
    u16* sAl = lds + 5120;
    u16* sBh = lds + 10240;
    u16* sBl = lds + 15360;
    const int tid  = threadIdx.x;
    const int m0 = blockIdx.y * 128, n0 = blockIdx.x * 128;
    const int w = tid >> 6, lane = tid & 63, quad = lane >> 4, l15 = lane & 15;
    const int wm = (w & 1) * 64, wn = (w >> 1) * 64;

    f32x4 acc[4][4] = {};

    for (int k0 = 0; k0 < K; k0 += 32) {
        __syncthreads();
        if (AMODE == 0) {
            #pragma unroll
            for (int s = 0; s < 4; ++s) {
                int slot = tid + s * 256;
                int m = slot >> 3, kg = (slot & 7) << 2;
                float4 v = *(const float4*)(Af + (size_t)(m0 + m) * K + k0 + kg);
                u16 h0 = f2bf(v.x), h1 = f2bf(v.y), h2 = f2bf(v.z), h3 = f2bf(v.w);
                ushort4 hv = {h0, h1, h2, h3};
                ushort4 lv = {f2bf(v.x - bf2f(h0)), f2bf(v.y - bf2f(h1)),
                              f2bf(v.z - bf2f(h2)), f2bf(v.w - bf2f(h3))};
                *(ushort4*)&sAh[m * 40 + kg] = hv;
                *(ushort4*)&sAl[m * 40 + kg] = lv;
            }
        } else {
            #pragma unroll
            for (int s = 0; s < 4; ++s) {
                int slot = tid + s * 256;
                int m = slot >> 3, ke = (slot & 7) << 2;   // 4 elems per uint4
                uint4 u = *(const uint4*)(Apk + (size_t)(m0 + m) * K + k0 + ke);
                ushort4 hv = {(u16)(u.x & 0xffff), (u16)(u.y & 0xffff),
                              (u16)(u.z & 0xffff), (u16)(u.w & 0xffff)};
                ushort4 lv = {(u16)(u.x >> 16), (u16)(u.y >> 16),
                              (u16)(u.z >> 16), (u16)(u.w >> 16)};
                *(ushort4*)&sAh[m * 40 + ke] = hv;
                *(ushort4*)&sAl[m * 40 + ke] = lv;
            }
        }
        // B planes [N,K] bf16 -> LDS
        #pragma unroll
        for (int s = 0; s < 4; ++s) {
            int slot = tid + s * 256;                 // 1024 slots, 512 per plane
            int n = (slot & 511) >> 2, ku = slot & 3; // 8 elems per uint4
            const u16* src = (slot < 512) ? Bhi : Blo;
            u16* dst = (slot < 512) ? sBh : sBl;
            uint4 u = *(const uint4*)(src + (size_t)(n0 + n) * K + k0 + ku * 8);
            *(uint4*)&dst[n * 40 + ku * 8] = u;
        }
        __syncthreads();

        short8 ah[4], al[4], bh[4], bl[4];
        const int ko = quad * 8;
        #pragma unroll
        for (int i = 0; i < 4; ++i) {
            int ar = wm + i * 16 + l15;
            int br = wn + i * 16 + l15;
            ah[i] = *(const short8*)&sAh[ar * 40 + ko];
            al[i] = *(const short8*)&sAl[ar * 40 + ko];
            bh[i] = *(const short8*)&sBh[br * 40 + ko];
            bl[i] = *(const short8*)&sBl[br * 40 + ko];
        }
        #pragma unroll
        for (int i = 0; i < 4; ++i)
            #pragma unroll
            for (int j = 0; j < 4; ++j) {
                acc[i][j] = __builtin_amdgcn_mfma_f32_16x16x32_bf16(ah[i], bh[j], acc[i][j], 0, 0, 0);
                acc[i][j] = __builtin_amdgcn_mfma_f32_16x16x32_bf16(ah[i], bl[j], acc[i][j], 0, 0, 0);
                acc[i][j] = __builtin_amdgcn_mfma_f32_16x16x32_bf16(al[i], bh[j], acc[i][j], 0, 0, 0);
            }
    }

    // epilogue. C/D layout: col = n-tile + l15, row = m-tile + quad*4 + r
    if (EPI <= 1) {
        float bn[4];
        #pragma unroll
        for (int j = 0; j < 4; ++j) bn[j] = bias[n0 + wn + j * 16 + l15];
        #pragma unroll
        for (int i = 0; i < 4; ++i)
            #pragma unroll
            for (int r = 0; r < 4; ++r) {
                int row = m0 + wm + i * 16 + quad * 4 + r;
                #pragma unroll
                for (int j = 0; j < 4; ++j) {
                    float v = acc[i][j][r] + bn[j];
                    if (EPI == 0) v = fmaxf(v, 0.f);
                    u16 h = f2bf(v); u16 l = f2bf(v - bf2f(h));
                    Opk[(size_t)row * N + n0 + wn + j * 16 + l15] = (u32)h | ((u32)l << 16);
                }
            }
    } else {
        float cs[4]; int cidx[4];
        #pragma unroll
        for (int j = 0; j < 4; ++j) {
            cidx[j] = n0 + wn + j * 16 + l15;
            cs[j] = bias[cidx[j]];
        }
        const int nparts = gridDim.x * 2;
        const int pslot  = blockIdx.x * 2 + (w >> 1);   // distinct per wave-column!
        #pragma unroll
        for (int i = 0; i < 4; ++i)
            #pragma unroll
            for (int r = 0; r < 4; ++r) {
                int row = m0 + wm + i * 16 + quad * 4 + r;
                float d1 = 3.4e38f, d2 = 3.4e38f; int i1 = 0x7fffffff;
                #pragma unroll
                for (int j = 0; j < 4; ++j) {
                    float v = fmaf(-2.0f, acc[i][j][r], cs[j]);
                    if (v < d1) { d2 = d1; d1 = v; i1 = cidx[j]; }
                    else d2 = fminf(d2, v);
                }
                #pragma unroll
                for (int mm = 1; mm < 16; mm <<= 1) {
                    float od1 = __shfl_xor(d1, mm, 64);
                    float od2 = __shfl_xor(d2, mm, 64);
                    int   oi1 = __shfl_xor(i1, mm, 64);
                    if (od1 < d1 || (od1 == d1 && oi1 < i1)) { d2 = fminf(d1, od2); d1 = od1; i1 = oi1; }
                    else d2 = fminf(d2, od1);
                }
                if (l15 == 0) {
                    float4 o = {d1, d2, __int_as_float(i1), 0.f};
                    *(float4*)&Opart[((size_t)row * nparts + pslot) * 4] = o;
                }
            }
    }
}

// ---------------------------------------------------------------------------
// zsq from packed z
// ---------------------------------------------------------------------------
__global__ __launch_bounds__(256) void zsq_pk(
    const u32* __restrict__ Zpk, float* __restrict__ zsq)
{
    int tok = blockIdx.x * 4 + (threadIdx.x >> 6);
    int lane = threadIdx.x & 63;
    uint4 u = *(const uint4*)(Zpk + (size_t)tok * CBD + lane * 4);
    float z0 = bf2f((u16)(u.x & 0xffff)) + bf2f((u16)(u.x >> 16));
    float z1 = bf2f((u16)(u.y & 0xffff)) + bf2f((u16)(u.y >> 16));
    float z2 = bf2f((u16)(u.z & 0xffff)) + bf2f((u16)(u.z >> 16));
    float z3 = bf2f((u16)(u.w & 0xffff)) + bf2f((u16)(u.w >> 16));
    float s = z0 * z0 + z1 * z1 + z2 * z2 + z3 * z3;
    #pragma unroll
    for (int off = 32; off; off >>= 1) s += __shfl_down(s, off, 64);
    if (!lane) zsq[tok] = s;
}

// ---------------------------------------------------------------------------
// combine per-slot top2 partials (8 per token) -> idx, flags, commit sum
// ---------------------------------------------------------------------------
__global__ __launch_bounds__(256) void vq_reduce(
    const float* __restrict__ part, const float* __restrict__ zsq,
    float* __restrict__ out_idx, int* __restrict__ idx_i,
    int* __restrict__ cnt, float* __restrict__ accum, int* __restrict__ flags)
{
    int tok = blockIdx.x * 256 + threadIdx.x;
    float d1 = 3.4e38f, d2 = 3.4e38f; int i1 = 0x7fffffff;
    #pragma unroll
    for (int nb = 0; nb < 8; ++nb) {
        float4 p = *(const float4*)&part[((size_t)tok * 8 + nb) * 4];
        float pd1 = p.x, pd2 = p.y; int pi1 = __float_as_int(p.z);
        if (pd1 < d1 || (pd1 == d1 && pi1 < i1)) { d2 = fminf(d1, pd2); d1 = pd1; i1 = pi1; }
        else d2 = fminf(d2, pd1);
    }
    out_idx[tok] = (float)i1;
    idx_i[tok] = i1;
    if (d2 - d1 < 0.05f) {
        int p = atomicAdd(cnt, 1);
        if (p >= 0 && p < NTOK) flags[p] = tok;
    }
    float c = zsq[tok] + d1;      // ||z||^2 + c_sq - 2 dot = ||z - q||^2
    __shared__ float red[256];
    red[threadIdx.x] = c; __syncthreads();
    for (int s = 128; s; s >>= 1) { if (threadIdx.x < s) red[threadIdx.x] += red[threadIdx.x + s]; __syncthreads(); }
    if (!threadIdx.x) atomicAdd(accum, red[0]);
}

// ---------------------------------------------------------------------------
// exact fp32 recompute of argmin for near-tie tokens
// ---------------------------------------------------------------------------
__global__ __launch_bounds__(256) void fixup(
    const int* __restrict__ cnt, const int* __restrict__ flags,
    const float* __restrict__ x, const float* __restrict__ W1, const float* __restrict__ b1,
    const float* __restrict__ W2, const float* __restrict__ b2,
    const float* __restrict__ cb, const float* __restrict__ csq,
    int* __restrict__ idx_i, float* __restrict__ out_idx)
{
    __shared__ float xs[IND], hs[HID], zs[CBD], ds[CBS];
    int n = cnt[0]; if (n > NTOK) n = NTOK; if (n < 0) n = 0;
    int t = threadIdx.x;
    for (int it = blockIdx.x; it < n; it += gridDim.x) {
        int tok = flags[it];
        if (t < 192) *(float4*)&xs[t * 4] = *(const float4*)(x + (size_t)tok * IND + t * 4);
        __syncthreads();
        #pragma unroll
        for (int s2 = 0; s2 < 2; ++s2) {
            int j = t + s2 * 256; float a = b1[j];
            for (int k = 0; k < IND; ++k) a = fmaf(xs[k], W1[(size_t)k * HID + j], a);
            hs[j] = fmaxf(a, 0.f);
        }
        __syncthreads();
        {
            float a = b2[t];
            for (int k = 0; k < HID; ++k) a = fmaf(hs[k], W2[(size_t)k * CBD + t], a);
            zs[t] = a;
        }
        __syncthreads();
        {
            int wv = t >> 6, l = t & 63;
            float4 zv = *(const float4*)&zs[l * 4];
            for (int cc = 0; cc < 128; ++cc) {
                int c = wv * 128 + cc;
                float4 cv = *(const float4*)(cb + (size_t)c * CBD + l * 4);
                float p = zv.x * cv.x + zv.y * cv.y + zv.z * cv.z + zv.w * cv.w;
                #pragma unroll
                for (int mm = 32; mm; mm >>= 1) p += __shfl_xor(p, mm, 64);
                if (!l) ds[c] = csq[c] - 2.f * p;
            }
        }
        __syncthreads();
        if (t < 64) {
            float bd = ds[t]; int bi = t;
            for (int c = t + 64; c < CBS; c += 64) {
                float d = ds[c];
                if (d < bd || (d == bd && c < bi)) { bd = d; bi = c; }
            }
            #pragma unroll
            for (int mm = 1; mm < 64; mm <<= 1) {
                float od = __shfl_xor(bd, mm, 64); int oi = __shfl_xor(bi, mm, 64);
                if (od < bd || (od == bd && oi < bi)) { bd = od; bi = oi; }
            }
            if (!t) { idx_i[tok] = bi; out_idx[tok] = (float)bi; }
        }
        __syncthreads();
    }
}

// ---------------------------------------------------------------------------
// ReconTable = decoder(codebook): one block per code
// ---------------------------------------------------------------------------
__global__ __launch_bounds__(256) void table_pre(
    const float* __restrict__ cb, const float* __restrict__ W3,
    const float* __restrict__ b3, const float* __restrict__ W4,
    const float* __restrict__ b4, float* __restrict__ table)
{
    __shared__ float crow[CBD];
    __shared__ float h2[HID];
    const int c = blockIdx.x;
    const int t = threadIdx.x;
    crow[t] = cb[(size_t)c * CBD + t];
    __syncthreads();
    #pragma unroll
    for (int s = 0; s < 2; ++s) {
        int j = t + s * 256;
        float acc = b3[j];
        for (int k = 0; k < CBD; ++k) acc = fmaf(crow[k], W3[(size_t)k * HID + j], acc);
        h2[j] = fmaxf(acc, 0.f);
    }
    __syncthreads();
    #pragma unroll
    for (int s = 0; s < 3; ++s) {
        int j = t + s * 256;
        float acc = b4[j];
        for (int k = 0; k < HID; ++k) acc = fmaf(h2[k], W4[(size_t)k * IND + j], acc);
        table[(size_t)c * IND + j] = acc;
    }
}

// ---------------------------------------------------------------------------
// recon gather
// ---------------------------------------------------------------------------
__global__ __launch_bounds__(256) void gather_kernel(
    const int* __restrict__ idx, const float* __restrict__ table,
    float* __restrict__ out)
{
    unsigned i = blockIdx.x * 256u + threadIdx.x;   // float4 index, total NTOK*192
    unsigned tok = i / 192u;
    unsigned c = i - tok * 192u;
    int id = idx[tok];
    ((float4*)out)[i] = ((const float4*)table)[(size_t)id * 192 + c];
}

__global__ void finalize_kernel(const float* __restrict__ accum,
                                float* __restrict__ out_loss)
{
    out_loss[0] = accum[0] * (1.0f / 16777216.0f);   // mean over NTOK*CBD
}

// ---------------------------------------------------------------------------
extern "C" void kernel_launch(void* const* d_in, const int* in_sizes, int n_in,
                              void* d_out, int out_size, void* d_ws, size_t ws_size,
                              hipStream_t stream) {
    const float* x  = (const float*)d_in[0];
    const float* W1 = (const float*)d_in[1];
    const float* b1 = (const float*)d_in[2];
    const float* W2 = (const float*)d_in[3];
    const float* b2 = (const float*)d_in[4];
    const float* cb = (const float*)d_in[5];
    const float* W3 = (const float*)d_in[6];
    const float* b3 = (const float*)d_in[7];
    const float* W4 = (const float*)d_in[8];
    const float* b4 = (const float*)d_in[9];

    char* ws = (char*)d_ws;
    u32*  Hpk   = (u32*)(ws + OFF_H);
    u32*  Zpk   = (u32*)(ws + OFF_Z);
    u16*  W1h   = (u16*)(ws + OFF_W1H);
    u16*  W1l   = (u16*)(ws + OFF_W1L);
    u16*  W2h   = (u16*)(ws + OFF_W2H);
    u16*  W2l   = (u16*)(ws + OFF_W2L);
    u16*  CBh   = (u16*)(ws + OFF_CBH);
    u16*  CBl   = (u16*)(ws + OFF_CBL);
    float* csq  = (float*)(ws + OFF_CSQ);
    float* part = (float*)(ws + OFF_PART);
    float* table = (float*)(ws + OFF_TABLE);
    float* zsq  = (float*)(ws + OFF_ZSQ);
    int*   idx_i = (int*)(ws + OFF_IDX);
    int*   flags = (int*)(ws + OFF_FLAGS);
    int*   cnt   = (int*)(ws + OFF_CNT);
    float* accum = (float*)(ws + OFF_CNT + 4);

    float* out      = (float*)d_out;
    float* out_idx  = out + OUT_IDX_OFF;
    float* out_loss = out + OUT_LOSS_OFF;

    cbsplit<<<CBS, 256, 0, stream>>>(cb, CBh, CBl, csq);
    wsplit<<<HID, 256, 0, stream>>>(W1, W1h, W1l, IND, HID);   // W1T [512][768]
    wsplit<<<CBD, 256, 0, stream>>>(W2, W2h, W2l, HID, CBD);   // W2T [256][512]

    // h = relu(x @ W1 + b1) -> packed planes
    gemm3<0, 0><<<dim3(HID / 128, NTOK / 128), 256, 0, stream>>>(
        x, (const u32*)nullptr, W1h, W1l, b1, Hpk, (float*)nullptr, NTOK, HID, IND);
    // z = h @ W2 + b2 -> packed planes
    gemm3<1, 1><<<dim3(CBD / 128, NTOK / 128), 256, 0, stream>>>(
        (const float*)nullptr, Hpk, W2h, W2l, b2, Zpk, (float*)nullptr, NTOK, CBD, HID);

    // H region is dead from here on; zero cnt/accum AFTER GEMM1's Hpk writes
    // (round-2 bug: zeroing first got clobbered -> garbage cnt -> OOB flags write)
    hipMemsetAsync(cnt, 0, 8, stream);

    zsq_pk<<<NTOK / 4, 256, 0, stream>>>(Zpk, zsq);

    // dists top-2 partials: dist = c_sq - 2 * (z . c)
    gemm3<1, 2><<<dim3(CBS / 128, NTOK / 128), 256, 0, stream>>>(
        (const float*)nullptr, Zpk, CBh, CBl, csq, (u32*)nullptr, part, NTOK, CBS, CBD);

    table_pre<<<CBS, 256, 0, stream>>>(cb, W3, b3, W4, b4, table);

    vq_reduce<<<NTOK / 256, 256, 0, stream>>>(part, zsq, out_idx, idx_i, cnt, accum, flags);

    fixup<<<192, 256, 0, stream>>>(cnt, flags, x, W1, b1, W2, b2, cb, csq, idx_i, out_idx);

    gather_kernel<<<(NTOK * (IND / 4)) / 256, 256, 0, stream>>>(idx_i, table, out);

    finalize_kernel<<<1, 1, 0, stream>>>(accum, out_loss);
}